// Round 1
// baseline (727.699 us; speedup 1.0000x reference)
//
#include <hip/hip_runtime.h>

// MultiHeadBiaffine: x(4,256,1024) fp32; Wh,Wv(512,1024); bh,bv(512); W(4,128,128,128)
// out (4,256,256,512) fp32.
// Decomposition:
//   h[b,l,h,x] = leaky(x @ Wh^T), v likewise        (k1, MFMA bf16)
//   u[b,h,l,d,y] = sum_x h * W[h,d,x,y]             (k2, MFMA bf16, all b batched)
//   out[b,l,k,h*128+d] = sum_y v[b,k,h,y]*u[...]    (k3, MFMA bf16, fp32 out)
// Workspace: Wb(16MiB) | hmat(1MiB) | vmat(1MiB) | u(128MiB all-b, or 32MiB per-b
// fallback) — batched path needs 146 MiB; harness ws is ~2 GiB.

typedef unsigned short u16;
typedef __attribute__((ext_vector_type(8))) short short8;
typedef __attribute__((ext_vector_type(4))) float f32x4;

typedef __attribute__((address_space(1))) const unsigned gu32;
typedef __attribute__((address_space(3))) unsigned lu32;

__device__ __forceinline__ u16 f2bf(float f) {
  union { float f; unsigned u; } c; c.f = f;
  unsigned u = c.u;
  return (u16)((u + 0x7FFFu + ((u >> 16) & 1u)) >> 16);  // RNE
}

__device__ __forceinline__ unsigned pack2(float a, float b) {
  return ((unsigned)f2bf(b) << 16) | (unsigned)f2bf(a);
}

__device__ __forceinline__ uint4 pack8(const float* __restrict__ g) {
  float4 f0 = *(const float4*)(g);
  float4 f1 = *(const float4*)(g + 4);
  uint4 o;
  o.x = pack2(f0.x, f0.y);
  o.y = pack2(f0.z, f0.w);
  o.z = pack2(f1.x, f1.y);
  o.w = pack2(f1.z, f1.w);
  return o;
}

// ---- k-step tile core for k1 only (LDS tiles [128 rows][32 k] bf16) ----
__device__ __forceinline__ void tile_compute(const u16* As, const u16* Bs,
                                             f32x4 acc[4][4], int wm, int wn,
                                             int frow, int kq) {
  short8 af[4], bfr[4];
#pragma unroll
  for (int i = 0; i < 4; ++i)
    af[i] = *(const short8*)(As + (size_t)(wm + i * 16 + frow) * 32 + kq);
#pragma unroll
  for (int j = 0; j < 4; ++j)
    bfr[j] = *(const short8*)(Bs + (size_t)(wn + j * 16 + frow) * 32 + kq);
#pragma unroll
  for (int i = 0; i < 4; ++i)
#pragma unroll
    for (int j = 0; j < 4; ++j)
      acc[i][j] = __builtin_amdgcn_mfma_f32_16x16x32_bf16(af[i], bfr[j], acc[i][j], 0, 0, 0);
}

// ---- full-K staging for k2/k3: 128x128 bf16 tile, contiguous in global ----
// LDS layout is k-major 16B units: unit q = c*128 + row (c = k-slot 0..15,
// row 0..127) holds global unit (row*16 + c). ds_read_b128 of a fragment then
// has lanes 0-15 reading 256 contiguous bytes -> zero bank conflicts, and the
// global_load_lds destination stays linear (wave base + lane*16) per m104.
__device__ __forceinline__ void stage_tile(const u16* __restrict__ g,
                                           u16* lds, int wave, int lane) {
#pragma unroll
  for (int t = 0; t < 8; ++t) {
    int qb = wave * 512 + t * 64;      // wave-uniform LDS unit base
    int q = qb + lane;
    const u16* src = g + (size_t)((q & 127) * 128 + (q >> 7) * 8);
    __builtin_amdgcn_global_load_lds((gu32*)src, (lu32*)(lds + (size_t)qb * 8),
                                     16, 0, 0);
  }
}

// Consume full K=128 from k-major LDS tiles: 4 k-windows x 16 MFMA, no barriers.
__device__ __forceinline__ void compute_fullK(const u16* As, const u16* Bs,
                                              f32x4 acc[4][4], int wm, int wn,
                                              int frow, int chi) {
#pragma unroll
  for (int ks = 0; ks < 4; ++ks) {
    int c = ks * 4 + chi;              // k-slot for this lane quarter
    short8 af[4], bfr[4];
#pragma unroll
    for (int i = 0; i < 4; ++i)
      af[i] = *(const short8*)(As + ((size_t)c * 128 + wm + i * 16 + frow) * 8);
#pragma unroll
    for (int j = 0; j < 4; ++j)
      bfr[j] = *(const short8*)(Bs + ((size_t)c * 128 + wn + j * 16 + frow) * 8);
#pragma unroll
    for (int i = 0; i < 4; ++i)
#pragma unroll
      for (int j = 0; j < 4; ++j)
        acc[i][j] = __builtin_amdgcn_mfma_f32_16x16x32_bf16(af[i], bfr[j], acc[i][j], 0, 0, 0);
  }
}

// ---- k0: W[h][d][x][y] fp32 -> Wb[h][d][y][x] bf16 (transpose last two dims) ----
__global__ __launch_bounds__(256) void k0_twp(const float* __restrict__ W,
                                              u16* __restrict__ Wb) {
  __shared__ u16 t[128][129];
  int slice = blockIdx.x;  // h*128+d
  const float* src = W + (size_t)slice * 16384;
  u16* dst = Wb + (size_t)slice * 16384;
  int tid = threadIdx.x;
  for (int e = tid; e < 16384; e += 256) {
    int xi = e >> 7, yi = e & 127;
    t[xi][yi] = f2bf(src[e]);
  }
  __syncthreads();
  for (int e = tid; e < 16384; e += 256) {
    int yi = e >> 7, xi = e & 127;
    dst[e] = t[xi][yi];
  }
}

// ---- k1: fused head/tail MLP. M=1024 rows (b,l), N=1024 ([Wh|Wv]), K=1024 ----
__global__ __launch_bounds__(256) void k1_mlp(const float* __restrict__ x,
                                              const float* __restrict__ Wh,
                                              const float* __restrict__ bh,
                                              const float* __restrict__ Wv,
                                              const float* __restrict__ bv,
                                              u16* __restrict__ hmat,
                                              u16* __restrict__ vmat) {
  __shared__ __align__(16) u16 As[128 * 32];
  __shared__ __align__(16) u16 Bs[128 * 32];
  int tid = threadIdx.x;
  int m0 = blockIdx.y * 128;
  int n0 = blockIdx.x * 128;
  bool isV = (n0 >= 512);
  const float* Wsel = isV ? Wv : Wh;
  const float* bsel = isV ? bv : bh;
  int nW = isV ? (n0 - 512) : n0;
  int wave = tid >> 6, lane = tid & 63;
  int wm = (wave & 1) * 64, wn = (wave >> 1) * 64;
  int r = tid >> 1, seg = tid & 1;
  int frow = lane & 15, kq = (lane >> 4) * 8;
  f32x4 acc[4][4];
  f32x4 z = {0.f, 0.f, 0.f, 0.f};
#pragma unroll
  for (int i = 0; i < 4; ++i)
#pragma unroll
    for (int j = 0; j < 4; ++j) acc[i][j] = z;

  for (int k0 = 0; k0 < 1024; k0 += 32) {
    const float* ga = x + (size_t)(m0 + r) * 1024 + k0 + seg * 16;
    const float* gb = Wsel + (size_t)(nW + r) * 1024 + k0 + seg * 16;
    uint4 a0 = pack8(ga), a1 = pack8(ga + 8);
    uint4 b0 = pack8(gb), b1 = pack8(gb + 8);
    __syncthreads();
    *(uint4*)(As + r * 32 + seg * 16) = a0;
    *(uint4*)(As + r * 32 + seg * 16 + 8) = a1;
    *(uint4*)(Bs + r * 32 + seg * 16) = b0;
    *(uint4*)(Bs + r * 32 + seg * 16 + 8) = b1;
    __syncthreads();
    tile_compute(As, Bs, acc, wm, wn, frow, kq);
  }

  u16* dst = isV ? vmat : hmat;
#pragma unroll
  for (int i = 0; i < 4; ++i)
#pragma unroll
    for (int j = 0; j < 4; ++j)
#pragma unroll
      for (int rg = 0; rg < 4; ++rg) {
        int ml = wm + i * 16 + (lane >> 4) * 4 + rg;
        int nl = wn + j * 16 + (lane & 15);
        int mg = m0 + ml;  // b*256+l
        int ng = n0 + nl;  // feature
        float val = acc[i][j][rg] + bsel[nW + nl];
        val = (val >= 0.f) ? val : 0.01f * val;
        int bb = mg >> 8, ll = mg & 255;
        int head = (ng & 511) >> 7, xcol = ng & 127;
        dst[(((size_t)(bb * 4 + head)) * 256 + ll) * 128 + xcol] = f2bf(val);
      }
}

// ---- k2: u[z][l][dy] = hmat[b][h] (256x128) @ Wb[h] (16384x128)^T, z=b*4+h ----
// Single full-K stage (K=128): one barrier, then 64 MFMA/wave.
__global__ __launch_bounds__(256) void k2_uw(const u16* __restrict__ hmat,
                                             const u16* __restrict__ Wb,
                                             u16* __restrict__ u, int b0) {
  __shared__ __align__(16) u16 As[16384];
  __shared__ __align__(16) u16 Bs[16384];
  int tid = threadIdx.x, wave = tid >> 6, lane = tid & 63;
  int z = blockIdx.z;
  int b = b0 + (z >> 2), h = z & 3;
  int n0 = blockIdx.x * 128;  // dy tile
  int m0 = blockIdx.y * 128;  // l tile
  const u16* A = hmat + ((size_t)(b * 4 + h) * 256 + m0) * 128;
  const u16* Bt = Wb + ((size_t)h * 16384 + n0) * 128;
  stage_tile(A, As, wave, lane);
  stage_tile(Bt, Bs, wave, lane);

  int wm = (wave & 1) * 64, wn = (wave >> 1) * 64;
  int frow = lane & 15, chi = lane >> 4;
  f32x4 acc[4][4];
  f32x4 zz = {0.f, 0.f, 0.f, 0.f};
#pragma unroll
  for (int i = 0; i < 4; ++i)
#pragma unroll
    for (int j = 0; j < 4; ++j) acc[i][j] = zz;

  __syncthreads();  // drains vmcnt(0): all global_load_lds complete
  compute_fullK(As, Bs, acc, wm, wn, frow, chi);

  u16* C = u + ((size_t)z * 256 + m0) * 16384 + n0;
#pragma unroll
  for (int i = 0; i < 4; ++i)
#pragma unroll
    for (int j = 0; j < 4; ++j)
#pragma unroll
      for (int rg = 0; rg < 4; ++rg) {
        int ml = wm + i * 16 + (lane >> 4) * 4 + rg;
        int nl = wn + j * 16 + (lane & 15);
        C[(size_t)ml * 16384 + nl] = f2bf(acc[i][j][rg]);
      }
}

// ---- k3: out[b][l][k][h*128+d] = vmat[b][h] (256x128) @ u[z][l] (128d x 128y)^T ----
// grid (l=256, ktile=2, z=16): k-tile pair of one l is 256 apart in linear id
// -> same XCD under %8 round-robin -> u tile L2-reused.
__global__ __launch_bounds__(256) void k3_out(const u16* __restrict__ vmat,
                                              const u16* __restrict__ u,
                                              float* __restrict__ out, int b0) {
  __shared__ __align__(16) u16 As[16384];
  __shared__ __align__(16) u16 Bs[16384];
  int tid = threadIdx.x, wave = tid >> 6, lane = tid & 63;
  int z = blockIdx.z;
  int b = b0 + (z >> 2), h = z & 3;
  int l = blockIdx.x;
  int k0t = blockIdx.y * 128;  // k tile
  const u16* A = vmat + ((size_t)(b * 4 + h) * 256 + k0t) * 128;  // [k][y]
  const u16* Bt = u + ((size_t)z * 256 + l) * 16384;              // [d][y]
  stage_tile(A, As, wave, lane);
  stage_tile(Bt, Bs, wave, lane);

  int wm = (wave & 1) * 64, wn = (wave >> 1) * 64;
  int frow = lane & 15, chi = lane >> 4;
  f32x4 acc[4][4];
  f32x4 zz = {0.f, 0.f, 0.f, 0.f};
#pragma unroll
  for (int i = 0; i < 4; ++i)
#pragma unroll
    for (int j = 0; j < 4; ++j) acc[i][j] = zz;

  __syncthreads();
  compute_fullK(As, Bs, acc, wm, wn, frow, chi);

#pragma unroll
  for (int i = 0; i < 4; ++i)
#pragma unroll
    for (int j = 0; j < 4; ++j)
#pragma unroll
      for (int rg = 0; rg < 4; ++rg) {
        int kk = k0t + wm + i * 16 + (lane >> 4) * 4 + rg;
        int d = wn + j * 16 + (lane & 15);
        out[(((size_t)b * 256 + l) * 256 + kk) * 512 + h * 128 + d] = acc[i][j][rg];
      }
}

extern "C" void kernel_launch(void* const* d_in, const int* in_sizes, int n_in,
                              void* d_out, int out_size, void* d_ws, size_t ws_size,
                              hipStream_t stream) {
  const float* x = (const float*)d_in[0];
  const float* Wh = (const float*)d_in[1];
  const float* bh = (const float*)d_in[2];
  const float* Wv = (const float*)d_in[3];
  const float* bv = (const float*)d_in[4];
  const float* W = (const float*)d_in[5];
  float* out = (float*)d_out;

  char* ws = (char*)d_ws;
  u16* Wb = (u16*)(ws);                    // 16 MiB: [4][128][128y][128x]
  u16* hmat = (u16*)(ws + (16u << 20));    // 1 MiB:  [4*4][256][128]
  u16* vmat = (u16*)(ws + (17u << 20));    // 1 MiB
  u16* u = (u16*)(ws + (18u << 20));       // 128 MiB batched: [16][256][16384]

  hipLaunchKernelGGL(k0_twp, dim3(512), dim3(256), 0, stream, W, Wb);
  hipLaunchKernelGGL(k1_mlp, dim3(8, 8), dim3(256), 0, stream, x, Wh, bh, Wv, bv,
                     hmat, vmat);

  size_t need = (18ull << 20) + (128ull << 20);
  if (ws_size >= need) {
    // all b in one launch each: 4 launches total, no WAR serialization
    hipLaunchKernelGGL(k2_uw, dim3(128, 2, 16), dim3(256), 0, stream, hmat, Wb, u, 0);
    hipLaunchKernelGGL(k3_out, dim3(256, 2, 16), dim3(256), 0, stream, vmat, u, out, 0);
  } else {
    // fallback: per-b chunks, u = 32 MiB (z = h only)
    for (int b = 0; b < 4; ++b) {
      hipLaunchKernelGGL(k2_uw, dim3(128, 2, 4), dim3(256), 0, stream, hmat, Wb, u, b);
      hipLaunchKernelGGL(k3_out, dim3(256, 2, 4), dim3(256), 0, stream, vmat, u, out, b);
    }
  }
}

// Round 2
// 678.108 us; speedup vs baseline: 1.0731x; 1.0731x over previous
//
#include <hip/hip_runtime.h>

// MultiHeadBiaffine: x(4,256,1024) fp32; Wh,Wv(512,1024); bh,bv(512); W(4,128,128,128)
// out (4,256,256,512) fp32.
//   h[b,l,h,x] = leaky(x @ Wh^T), v likewise        (k1, MFMA bf16)
//   u[z][l][dy] = hmat @ Wb^T                       (k2, MFMA bf16)
//   out[b,l,k,h*128+d] = vmat @ u^T                 (k3, MFMA bf16, fp32 out)
// Staging discipline (round-2 fix): every global_load_lds is COALESCED.
//  R1: producer (k0/k1 epilogue, scalar stores anyway) emits tiles in k-major
//      unit order [c16][row128][8elem]; consumer stages with a pure linear
//      copy and reads conflict-free (256B per 16-lane group).
//  R2: u stays row-major (keeps k2's 128B-contiguous writes); k3 stages it
//      with source permuted only WITHIN each 256B row (c ^= row&7) and reads
//      with the same XOR -> 2-way bank aliasing (free), coalescing intact.

typedef unsigned short u16;
typedef __attribute__((ext_vector_type(8))) short short8;
typedef __attribute__((ext_vector_type(4))) float f32x4;

typedef __attribute__((address_space(1))) const unsigned gu32;
typedef __attribute__((address_space(3))) unsigned lu32;

__device__ __forceinline__ u16 f2bf(float f) {
  union { float f; unsigned u; } c; c.f = f;
  unsigned u = c.u;
  return (u16)((u + 0x7FFFu + ((u >> 16) & 1u)) >> 16);  // RNE
}

__device__ __forceinline__ unsigned pack2(float a, float b) {
  return ((unsigned)f2bf(b) << 16) | (unsigned)f2bf(a);
}

__device__ __forceinline__ uint4 pack8(const float* __restrict__ g) {
  float4 f0 = *(const float4*)(g);
  float4 f1 = *(const float4*)(g + 4);
  uint4 o;
  o.x = pack2(f0.x, f0.y);
  o.y = pack2(f0.z, f0.w);
  o.z = pack2(f1.x, f1.y);
  o.w = pack2(f1.z, f1.w);
  return o;
}

// ---- R1 stage: tile already stored in k-major unit order; pure linear copy.
// 2048 units x 16B; 4 waves x 8 iters x 64 lanes. Fully coalesced (1KiB/instr).
__device__ __forceinline__ void stage_linear(const u16* __restrict__ g,
                                             u16* lds, int wave, int lane) {
#pragma unroll
  for (int t = 0; t < 8; ++t) {
    int qb = wave * 512 + t * 64;
    __builtin_amdgcn_global_load_lds((gu32*)(g + (size_t)(qb + lane) * 8),
                                     (lu32*)(lds + (size_t)qb * 8), 16, 0, 0);
  }
}

// ---- R2 stage: row-major [128][128] bf16 tile; source XOR-permuted within
// each 256B row (coalesced: 4 full rows per instr, permuted inside).
__device__ __forceinline__ void stage_xor(const u16* __restrict__ g,
                                          u16* lds, int wave, int lane) {
#pragma unroll
  for (int t = 0; t < 8; ++t) {
    int qb = wave * 512 + t * 64;
    int q = qb + lane;
    int row = q >> 4, c = q & 15;
    int su = row * 16 + (c ^ (row & 7));
    __builtin_amdgcn_global_load_lds((gu32*)(g + (size_t)su * 8),
                                     (lu32*)(lds + (size_t)qb * 8), 16, 0, 0);
  }
}

// ---- consume K=128, both tiles k-major: addr (c*128+row)*16B, conflict-free.
__device__ __forceinline__ void compute_kk(const u16* As, const u16* Bs,
                                           f32x4 acc[4][4], int wm, int wn,
                                           int frow, int chi) {
#pragma unroll
  for (int ks = 0; ks < 4; ++ks) {
    int c = ks * 4 + chi;
    short8 af[4], bfr[4];
#pragma unroll
    for (int i = 0; i < 4; ++i)
      af[i] = *(const short8*)(As + ((size_t)c * 128 + wm + i * 16 + frow) * 8);
#pragma unroll
    for (int j = 0; j < 4; ++j)
      bfr[j] = *(const short8*)(Bs + ((size_t)c * 128 + wn + j * 16 + frow) * 8);
#pragma unroll
    for (int i = 0; i < 4; ++i)
#pragma unroll
      for (int j = 0; j < 4; ++j)
        acc[i][j] = __builtin_amdgcn_mfma_f32_16x16x32_bf16(af[i], bfr[j], acc[i][j], 0, 0, 0);
  }
}

// ---- consume K=128, A k-major, B row-major with XOR (matches stage_xor).
__device__ __forceinline__ void compute_kx(const u16* As, const u16* Bs,
                                           f32x4 acc[4][4], int wm, int wn,
                                           int frow, int chi) {
#pragma unroll
  for (int ks = 0; ks < 4; ++ks) {
    int c = ks * 4 + chi;
    short8 af[4], bfr[4];
#pragma unroll
    for (int i = 0; i < 4; ++i)
      af[i] = *(const short8*)(As + ((size_t)c * 128 + wm + i * 16 + frow) * 8);
#pragma unroll
    for (int j = 0; j < 4; ++j) {
      int rn = wn + j * 16 + frow;
      bfr[j] = *(const short8*)(Bs + ((size_t)rn * 16 + (c ^ (rn & 7))) * 8);
    }
#pragma unroll
    for (int i = 0; i < 4; ++i)
#pragma unroll
      for (int j = 0; j < 4; ++j)
        acc[i][j] = __builtin_amdgcn_mfma_f32_16x16x32_bf16(af[i], bfr[j], acc[i][j], 0, 0, 0);
  }
}

// ---- k0: W[h][d][x][y] fp32 -> Wb[h*128+d] in k-major units [cx16][y128][8x] ----
__global__ __launch_bounds__(256) void k0_twp(const float* __restrict__ W,
                                              u16* __restrict__ Wb) {
  __shared__ u16 t[128][129];  // t[x][y]
  int slice = blockIdx.x;  // h*128+d
  const float* src = W + (size_t)slice * 16384;
  u16* dst = Wb + (size_t)slice * 16384;
  int tid = threadIdx.x;
  for (int e = tid; e < 16384; e += 256) {
    int xi = e >> 7, yi = e & 127;
    t[xi][yi] = f2bf(src[e]);
  }
  __syncthreads();
  // e = c*1024 + y*8 + xl  ->  element W[..][x=8c+xl][y]
  for (int e = tid; e < 16384; e += 256) {
    int c = e >> 10, rem = e & 1023, y = rem >> 3, xl = rem & 7;
    dst[e] = t[c * 8 + xl][y];
  }
}

// ---- k1: fused head/tail MLP. M=1024 rows (b,l), N=1024 ([Wh|Wv]), K=1024 ----
// Epilogue emits hmat/vmat tiles in R1 k-major unit order, indexed zi=h*4+b.
__global__ __launch_bounds__(256) void k1_mlp(const float* __restrict__ x,
                                              const float* __restrict__ Wh,
                                              const float* __restrict__ bh,
                                              const float* __restrict__ Wv,
                                              const float* __restrict__ bv,
                                              u16* __restrict__ hmat,
                                              u16* __restrict__ vmat) {
  __shared__ __align__(16) u16 As[128 * 32];
  __shared__ __align__(16) u16 Bs[128 * 32];
  int tid = threadIdx.x;
  int m0 = blockIdx.y * 128;
  int n0 = blockIdx.x * 128;
  bool isV = (n0 >= 512);
  const float* Wsel = isV ? Wv : Wh;
  const float* bsel = isV ? bv : bh;
  int nW = isV ? (n0 - 512) : n0;
  int wave = tid >> 6, lane = tid & 63;
  int wm = (wave & 1) * 64, wn = (wave >> 1) * 64;
  int r = tid >> 1, seg = tid & 1;
  int frow = lane & 15, kq = (lane >> 4) * 8;
  f32x4 acc[4][4];
  f32x4 z = {0.f, 0.f, 0.f, 0.f};
#pragma unroll
  for (int i = 0; i < 4; ++i)
#pragma unroll
    for (int j = 0; j < 4; ++j) acc[i][j] = z;

  for (int k0 = 0; k0 < 1024; k0 += 32) {
    const float* ga = x + (size_t)(m0 + r) * 1024 + k0 + seg * 16;
    const float* gb = Wsel + (size_t)(nW + r) * 1024 + k0 + seg * 16;
    uint4 a0 = pack8(ga), a1 = pack8(ga + 8);
    uint4 b0 = pack8(gb), b1 = pack8(gb + 8);
    __syncthreads();
    *(uint4*)(As + r * 32 + seg * 16) = a0;
    *(uint4*)(As + r * 32 + seg * 16 + 8) = a1;
    *(uint4*)(Bs + r * 32 + seg * 16) = b0;
    *(uint4*)(Bs + r * 32 + seg * 16 + 8) = b1;
    __syncthreads();
    // inline tile compute ([128 rows][32 k] LDS layout)
    short8 af[4], bfr[4];
#pragma unroll
    for (int i = 0; i < 4; ++i)
      af[i] = *(const short8*)(As + (size_t)(wm + i * 16 + frow) * 32 + kq);
#pragma unroll
    for (int j = 0; j < 4; ++j)
      bfr[j] = *(const short8*)(Bs + (size_t)(wn + j * 16 + frow) * 32 + kq);
#pragma unroll
    for (int i = 0; i < 4; ++i)
#pragma unroll
      for (int j = 0; j < 4; ++j)
        acc[i][j] = __builtin_amdgcn_mfma_f32_16x16x32_bf16(af[i], bfr[j], acc[i][j], 0, 0, 0);
  }

  u16* dst = isV ? vmat : hmat;
#pragma unroll
  for (int i = 0; i < 4; ++i)
#pragma unroll
    for (int j = 0; j < 4; ++j)
#pragma unroll
      for (int rg = 0; rg < 4; ++rg) {
        int ml = wm + i * 16 + (lane >> 4) * 4 + rg;
        int nl = wn + j * 16 + (lane & 15);
        int mg = m0 + ml;  // b*256+l
        int ng = n0 + nl;  // feature
        float val = acc[i][j][rg] + bsel[nW + nl];
        val = (val >= 0.f) ? val : 0.01f * val;
        int bb = mg >> 8, ll = mg & 255;
        int head = (ng & 511) >> 7, xc = ng & 127;
        int zi = head * 4 + bb;
        // R1 unit order: [zi][ltile2][cx16][row128][8x]
        dst[((size_t)zi * 2 + (ll >> 7)) * 16384 + (xc >> 3) * 1024 +
            (ll & 127) * 8 + (xc & 7)] = f2bf(val);
      }
}

// ---- k2: u[zi][l][d*128+y] = hmat[zi] (256x128x) @ Wb[h][d] (128y x 128x)^T ----
// z-grid h-major: zi = h*4+b -> Wb tile reused by 8 consecutive-ish same-XCD
// blocks (ids differ by 256), L2-resident (2 MiB/XCD).
__global__ __launch_bounds__(256) void k2_uw(const u16* __restrict__ hmat,
                                             const u16* __restrict__ Wb,
                                             u16* __restrict__ u, int b0, int nz) {
  __shared__ __align__(16) u16 As[16384];
  __shared__ __align__(16) u16 Bs[16384];
  int tid = threadIdx.x, wave = tid >> 6, lane = tid & 63;
  int zz = blockIdx.z;
  int h, b;
  if (nz == 16) { h = zz >> 2; b = zz & 3; } else { h = zz; b = b0; }
  int zi_hm = h * 4 + b;   // hmat index
  int zi_u = zz;           // u chunk index (batched: h*4+b; fallback: h)
  int d = blockIdx.x;      // 0..127
  int m0 = blockIdx.y * 128;
  stage_linear(hmat + ((size_t)zi_hm * 2 + (m0 >> 7)) * 16384, As, wave, lane);
  stage_linear(Wb + ((size_t)h * 128 + d) * 16384, Bs, wave, lane);

  int wm = (wave & 1) * 64, wn = (wave >> 1) * 64;
  int frow = lane & 15, chi = lane >> 4;
  f32x4 acc[4][4];
  f32x4 zz4 = {0.f, 0.f, 0.f, 0.f};
#pragma unroll
  for (int i = 0; i < 4; ++i)
#pragma unroll
    for (int j = 0; j < 4; ++j) acc[i][j] = zz4;

  __syncthreads();  // drains vmcnt(0): all global_load_lds complete
  compute_kk(As, Bs, acc, wm, wn, frow, chi);

  u16* C = u + ((size_t)zi_u * 256 + m0) * 16384 + (d << 7);
#pragma unroll
  for (int i = 0; i < 4; ++i)
#pragma unroll
    for (int j = 0; j < 4; ++j)
#pragma unroll
      for (int rg = 0; rg < 4; ++rg) {
        int ml = wm + i * 16 + (lane >> 4) * 4 + rg;
        int nl = wn + j * 16 + (lane & 15);
        C[(size_t)ml * 16384 + nl] = f2bf(acc[i][j][rg]);
      }
}

// ---- k3: out[b][l][k][h*128+d] = vmat[zi] (256k x 128y) @ u[zi][l] (128d x 128y)^T
// grid (l=256, ktile=2, z): k-tile pair 256 apart in linear id -> same XCD,
// u tile read once from HBM + once from L2.
__global__ __launch_bounds__(256) void k3_out(const u16* __restrict__ vmat,
                                              const u16* __restrict__ u,
                                              float* __restrict__ out, int b0, int nz) {
  __shared__ __align__(16) u16 As[16384];
  __shared__ __align__(16) u16 Bs[16384];
  int tid = threadIdx.x, wave = tid >> 6, lane = tid & 63;
  int zz = blockIdx.z;
  int h, b;
  if (nz == 16) { h = zz >> 2; b = zz & 3; } else { h = zz; b = b0; }
  int zi_vm = h * 4 + b;
  int zi_u = zz;
  int l = blockIdx.x;
  int k0t = blockIdx.y * 128;
  stage_linear(vmat + ((size_t)zi_vm * 2 + (k0t >> 7)) * 16384, As, wave, lane);
  stage_xor(u + ((size_t)zi_u * 256 + l) * 16384, Bs, wave, lane);

  int wm = (wave & 1) * 64, wn = (wave >> 1) * 64;
  int frow = lane & 15, chi = lane >> 4;
  f32x4 acc[4][4];
  f32x4 zz4 = {0.f, 0.f, 0.f, 0.f};
#pragma unroll
  for (int i = 0; i < 4; ++i)
#pragma unroll
    for (int j = 0; j < 4; ++j) acc[i][j] = zz4;

  __syncthreads();
  compute_kx(As, Bs, acc, wm, wn, frow, chi);

#pragma unroll
  for (int i = 0; i < 4; ++i)
#pragma unroll
    for (int j = 0; j < 4; ++j)
#pragma unroll
      for (int rg = 0; rg < 4; ++rg) {
        int kk = k0t + wm + i * 16 + (lane >> 4) * 4 + rg;
        int dd = wn + j * 16 + (lane & 15);
        out[(((size_t)b * 256 + l) * 256 + kk) * 512 + h * 128 + dd] = acc[i][j][rg];
      }
}

extern "C" void kernel_launch(void* const* d_in, const int* in_sizes, int n_in,
                              void* d_out, int out_size, void* d_ws, size_t ws_size,
                              hipStream_t stream) {
  const float* x = (const float*)d_in[0];
  const float* Wh = (const float*)d_in[1];
  const float* bh = (const float*)d_in[2];
  const float* Wv = (const float*)d_in[3];
  const float* bv = (const float*)d_in[4];
  const float* W = (const float*)d_in[5];
  float* out = (float*)d_out;

  char* ws = (char*)d_ws;
  u16* Wb = (u16*)(ws);                    // 16 MiB: [h][d] tiles, R1 unit order
  u16* hmat = (u16*)(ws + (16u << 20));    // 1 MiB:  [zi][ltile][R1 units]
  u16* vmat = (u16*)(ws + (17u << 20));    // 1 MiB
  u16* u = (u16*)(ws + (18u << 20));       // 128 MiB batched: [zi][256][16384]

  hipLaunchKernelGGL(k0_twp, dim3(512), dim3(256), 0, stream, W, Wb);
  hipLaunchKernelGGL(k1_mlp, dim3(8, 8), dim3(256), 0, stream, x, Wh, bh, Wv, bv,
                     hmat, vmat);

  size_t need = (18ull << 20) + (128ull << 20);
  if (ws_size >= need) {
    hipLaunchKernelGGL(k2_uw, dim3(128, 2, 16), dim3(256), 0, stream, hmat, Wb, u, 0, 16);
    hipLaunchKernelGGL(k3_out, dim3(256, 2, 16), dim3(256), 0, stream, vmat, u, out, 0, 16);
  } else {
    for (int b = 0; b < 4; ++b) {
      hipLaunchKernelGGL(k2_uw, dim3(128, 2, 4), dim3(256), 0, stream, hmat, Wb, u, b, 4);
      hipLaunchKernelGGL(k3_out, dim3(256, 2, 4), dim3(256), 0, stream, vmat, u, out, b, 4);
    }
  }
}